// Round 6
// baseline (25.349 us; speedup 1.0000x reference)
//
#include <hip/hip_runtime.h>

// out[b] = (x[b] @ Wv + bv) @ Wo + bo   (reference collapses: x broadcast over
// seq makes q/k/v seq-constant -> softmax exactly uniform -> attn@v == v ->
// seq-row 0 of o-proj = v@Wo+bo). Wq/bq/Wk/bk mathematically unused.
//
// BARRIER-FREE fusion (rounds 4/5 showed any grid barrier costs ~8 us via
// agent-scope fence L2 writeback/invalidate on non-coherent XCD L2s):
// block s owns t-columns [16s,16s+16): computes that t-slice COMPLETELY
// (leg1: Wv[:,slice], 64 KB), then its rank-16 contribution to ALL of out
// (leg2: contiguous strip Wo[slice,:], 64 KB), combined across blocks with
// plain fp32 atomicAdd (order-free). Weights read exactly once (8 MB total).
// out zero-initialized by a 16 KB memset node; bo added by block 0 only.
// Wo loads issued at kernel start (independent of leg1) -> one latency window.

namespace {

constexpr int CD   = 1024;  // C
constexpr int BN   = 4;     // B
constexpr int SW   = 16;    // t-cols per block
constexpr int NBLK = CD / SW;  // 64 blocks
constexpr int NT   = 1024;  // threads per block

__global__ __launch_bounds__(NT, 1)
void fused_attn(const float* __restrict__ x,
                const float* __restrict__ Wv, const float* __restrict__ bv,
                const float* __restrict__ Wo, const float* __restrict__ bo,
                float* __restrict__ out)
{
    __shared__ float xs[BN * CD];       // 16 KB
    __shared__ float wol[SW * CD];      // 64 KB: Wo strip
    __shared__ float red[16][4][16];    // 4 KB: [wave][cg][j*4+b]
    __shared__ float ts[BN][SW];        // t slice

    const int tid = threadIdx.x;
    const int c0  = blockIdx.x * SW;

    // ---- issue ALL global loads up front (one latency window) ----
    const int cg = tid & 3;             // float4 col-group within strip
    const int rs = tid >> 2;            // rowslice 0..255
    // Wv strip: lanes 0-3 read one row's 64 B contiguous -> 16 rows/wave-instr
    float4 wv[4];
#pragma unroll
    for (int p = 0; p < 4; ++p) {
        const int r = rs + 256 * p;
        wv[p] = *(const float4*)(Wv + (size_t)r * CD + c0 + cg * 4);
    }
    // Wo strip rows c0..c0+15 are CONTIGUOUS 64 KB at Wo + c0*CD: linear copy
    const float4* wos = (const float4*)(Wo + (size_t)c0 * CD);
    float4 wo[4];
#pragma unroll
    for (int k = 0; k < 4; ++k) wo[k] = wos[k * NT + tid];
    // x (16 KB)
    const float4 xv = ((const float4*)x)[tid];

    // ---- stage LDS ----
#pragma unroll
    for (int k = 0; k < 4; ++k) ((float4*)wol)[k * NT + tid] = wo[k];
    ((float4*)xs)[tid] = xv;
    __syncthreads();

    // ---- leg 1: t[b][c0+col] = bv + sum_r x[b][r] * Wv[r][c0+col] ----
    float a[4][4];                      // [j][b]
#pragma unroll
    for (int j = 0; j < 4; ++j)
#pragma unroll
        for (int b = 0; b < BN; ++b) a[j][b] = 0.f;

#pragma unroll
    for (int p = 0; p < 4; ++p) {
        const int r = rs + 256 * p;
        float xb[BN];
#pragma unroll
        for (int b = 0; b < BN; ++b) xb[b] = xs[b * CD + r];  // 4-lane broadcast
#pragma unroll
        for (int b = 0; b < BN; ++b) {
            a[0][b] = fmaf(xb[b], wv[p].x, a[0][b]);
            a[1][b] = fmaf(xb[b], wv[p].y, a[1][b]);
            a[2][b] = fmaf(xb[b], wv[p].z, a[2][b]);
            a[3][b] = fmaf(xb[b], wv[p].w, a[3][b]);
        }
    }
    // reduce over rowslices within wave (lane bits 2..5); cg preserved
#pragma unroll
    for (int s = 4; s < 64; s <<= 1)
#pragma unroll
        for (int j = 0; j < 4; ++j)
#pragma unroll
            for (int b = 0; b < BN; ++b)
                a[j][b] += __shfl_xor(a[j][b], s, 64);

    const int lane = tid & 63, wv_id = tid >> 6;
    if (lane < 4) {                     // lane == cg
#pragma unroll
        for (int j = 0; j < 4; ++j)
#pragma unroll
            for (int b = 0; b < BN; ++b)
                red[wv_id][lane][j * 4 + b] = a[j][b];
    }
    __syncthreads();

    if (tid < SW * BN) {                // 64 finals
        const int col = tid >> 2, b = tid & 3;
        float s = 0.f;
#pragma unroll
        for (int w = 0; w < 16; ++w)
            s += red[w][col >> 2][(col & 3) * 4 + b];
        ts[b][col] = s + bv[c0 + col];
    }
    __syncthreads();

    // ---- leg 2 (threads 0..255): out[b][4g+j] += sum_c ts[b][c]*Wo[c0+c][4g+j]
    if (tid < 256) {
        const int g = tid;
        float acc[BN][4];
#pragma unroll
        for (int b = 0; b < BN; ++b)
#pragma unroll
            for (int j = 0; j < 4; ++j) acc[b][j] = 0.f;

#pragma unroll
        for (int c = 0; c < SW; ++c) {
            const float4 w4 = *(const float4*)(wol + c * CD + g * 4);
            const float t0 = ts[0][c], t1 = ts[1][c], t2 = ts[2][c], t3 = ts[3][c];
            acc[0][0] = fmaf(t0, w4.x, acc[0][0]); acc[0][1] = fmaf(t0, w4.y, acc[0][1]);
            acc[0][2] = fmaf(t0, w4.z, acc[0][2]); acc[0][3] = fmaf(t0, w4.w, acc[0][3]);
            acc[1][0] = fmaf(t1, w4.x, acc[1][0]); acc[1][1] = fmaf(t1, w4.y, acc[1][1]);
            acc[1][2] = fmaf(t1, w4.z, acc[1][2]); acc[1][3] = fmaf(t1, w4.w, acc[1][3]);
            acc[2][0] = fmaf(t2, w4.x, acc[2][0]); acc[2][1] = fmaf(t2, w4.y, acc[2][1]);
            acc[2][2] = fmaf(t2, w4.z, acc[2][2]); acc[2][3] = fmaf(t2, w4.w, acc[2][3]);
            acc[3][0] = fmaf(t3, w4.x, acc[3][0]); acc[3][1] = fmaf(t3, w4.y, acc[3][1]);
            acc[3][2] = fmaf(t3, w4.z, acc[3][2]); acc[3][3] = fmaf(t3, w4.w, acc[3][3]);
        }
        if (blockIdx.x == 0) {          // bias added exactly once per element
            const float4 b4 = *(const float4*)(bo + g * 4);
#pragma unroll
            for (int b = 0; b < BN; ++b) {
                acc[b][0] += b4.x; acc[b][1] += b4.y;
                acc[b][2] += b4.z; acc[b][3] += b4.w;
            }
        }
#pragma unroll
        for (int b = 0; b < BN; ++b)
#pragma unroll
            for (int j = 0; j < 4; ++j)
                atomicAdd(&out[b * CD + g * 4 + j], acc[b][j]);
    }
}

} // namespace

extern "C" void kernel_launch(void* const* d_in, const int* in_sizes, int n_in,
                              void* d_out, int out_size, void* d_ws, size_t ws_size,
                              hipStream_t stream)
{
    // setup_inputs() order: x, Wq, bq, Wk, bk, Wv, bv, Wo, bo  (all fp32)
    const float* x  = (const float*)d_in[0];
    const float* Wv = (const float*)d_in[5];
    const float* bv = (const float*)d_in[6];
    const float* Wo = (const float*)d_in[7];
    const float* bo = (const float*)d_in[8];
    float* out = (float*)d_out;

    hipMemsetAsync(out, 0, (size_t)out_size * sizeof(float), stream);
    fused_attn<<<NBLK, NT, 0, stream>>>(x, Wv, bv, Wo, bo, out);
}

// Round 7
// 14.889 us; speedup vs baseline: 1.7025x; 1.7025x over previous
//
#include <hip/hip_runtime.h>

// out[b] = (x[b] @ Wv + bv) @ Wo + bo   (reference collapses: x broadcast over
// seq makes q/k/v seq-constant -> softmax exactly uniform -> attn@v == v ->
// seq-row 0 of o-proj = v@Wo+bo). Wq/bq/Wk/bk mathematically unused.
//
// Lessons R3-R6: grid barriers (agent fences), atomics into small regions,
// and hipMemsetAsync nodes (rocclr fill = ~40 us regardless of size) all lose
// to plain in-stream ordering of two lean kernels. So: two dispatches, each a
// latency-optimized matvec:
//   64 blocks x 1024 threads; block owns 16 output cols; per-wave W reads =
//   16 rows x 64 B contiguous float4 segments; X read directly (L1-hot,
//   4-lane broadcast); 4-level shfl_xor reduce + one 4 KB LDS combine;
//   exactly one __syncthreads per kernel. Weights read exactly once (8 MB,
//   L2/L3-resident across replays per FETCH_SIZE~15KB in all rounds).

namespace {

constexpr int CD   = 1024;  // C
constexpr int BN   = 4;     // B
constexpr int SW   = 16;    // output cols per block
constexpr int NBLK = CD / SW;   // 64
constexpr int NT   = 1024;

// Y[b][i] = sum_c X[b][c] * W[c][i] + bias[i]   for i in [16*blk, 16*blk+16)
__global__ __launch_bounds__(NT)
void matvec16(const float* __restrict__ X,    // [4][1024]
              const float* __restrict__ W,    // [1024][1024] ([in][out])
              const float* __restrict__ bias, // [1024]
              float* __restrict__ Y)          // [4][1024]
{
    __shared__ float red[16][64];   // [wave][cg*16 + j*4 + b]  (4 KB)

    const int tid = threadIdx.x;
    const int cg  = tid & 3;        // float4 col-group within 16-col strip
    const int rs  = tid >> 2;       // row-slice 0..255
    const int c0  = blockIdx.x * SW;

    // Issue all W loads first: per wave-instr, 16 consecutive rows x 64 B
    // contiguous (lanes 0-3 cover one row's 16 cols).
    float4 w4[4];
#pragma unroll
    for (int p = 0; p < 4; ++p)
        w4[p] = *(const float4*)(W + (size_t)(rs + 256 * p) * CD + c0 + cg * 4);

    float a[4][4];                  // [col j in float4][batch b]
#pragma unroll
    for (int j = 0; j < 4; ++j)
#pragma unroll
        for (int b = 0; b < BN; ++b) a[j][b] = 0.f;

#pragma unroll
    for (int p = 0; p < 4; ++p) {
        const int r = rs + 256 * p;
        float xb[BN];
#pragma unroll
        for (int b = 0; b < BN; ++b) xb[b] = X[b * CD + r];  // L1-hot, 4-lane bcast
#pragma unroll
        for (int b = 0; b < BN; ++b) {
            a[0][b] = fmaf(xb[b], w4[p].x, a[0][b]);
            a[1][b] = fmaf(xb[b], w4[p].y, a[1][b]);
            a[2][b] = fmaf(xb[b], w4[p].z, a[2][b]);
            a[3][b] = fmaf(xb[b], w4[p].w, a[3][b]);
        }
    }

    // Reduce over row-slices within the wave (lane bits 2..5; cg preserved).
#pragma unroll
    for (int s = 4; s < 64; s <<= 1)
#pragma unroll
        for (int j = 0; j < 4; ++j)
#pragma unroll
            for (int b = 0; b < BN; ++b)
                a[j][b] += __shfl_xor(a[j][b], s, 64);

    const int lane = tid & 63, wv = tid >> 6;
    if (lane < 4) {                 // lane == cg here
#pragma unroll
        for (int j = 0; j < 4; ++j)
#pragma unroll
            for (int b = 0; b < BN; ++b)
                red[wv][lane * 16 + j * 4 + b] = a[j][b];
    }
    __syncthreads();

    // 64 finals: col = tid>>2 (0..15), b = tid&3. Per-instr LDS reads are 64
    // consecutive floats -> conflict-free.
    if (tid < 64) {
        const int col = tid >> 2, b = tid & 3;
        const int idx = (col >> 2) * 16 + (col & 3) * 4 + b;
        float s = 0.f;
#pragma unroll
        for (int w = 0; w < 16; ++w) s += red[w][idx];
        Y[b * CD + c0 + col] = s + bias[c0 + col];
    }
}

} // namespace

extern "C" void kernel_launch(void* const* d_in, const int* in_sizes, int n_in,
                              void* d_out, int out_size, void* d_ws, size_t ws_size,
                              hipStream_t stream)
{
    // setup_inputs() order: x, Wq, bq, Wk, bk, Wv, bv, Wo, bo  (all fp32)
    const float* x  = (const float*)d_in[0];
    const float* Wv = (const float*)d_in[5];
    const float* bv = (const float*)d_in[6];
    const float* Wo = (const float*)d_in[7];
    const float* bo = (const float*)d_in[8];
    float* out = (float*)d_out;
    float* t   = (float*)d_ws;      // [4][1024] intermediate (16 KB)

    matvec16<<<NBLK, NT, 0, stream>>>(x, Wv, bv, t);
    matvec16<<<NBLK, NT, 0, stream>>>(t, Wo, bo, out);
}

// Round 8
// 14.695 us; speedup vs baseline: 1.7250x; 1.0132x over previous
//
#include <hip/hip_runtime.h>

// out[b] = (x[b] @ Wv + bv) @ Wo + bo   (reference collapses: x broadcast over
// seq makes q/k/v seq-constant -> softmax exactly uniform -> attn@v == v ->
// seq-row 0 of o-proj = v@Wo+bo). Wq/bq/Wk/bk mathematically unused.
//
// Structure = round 2's measured best (13.8 us): two in-stream dispatches,
// 128 blocks x 256 threads, block owns 8 output cols, K split 32-way
// interleaved, X staged in LDS. Sessions R3-R7 established:
//   - grid barriers / device atomics / memset nodes each cost +7-12 us
//     (non-coherent per-XCD L2s make agent-scope sync expensive);
//   - fixed graph-replay overhead ~10-11 us dominates; kernels ~1.5 us each.
// Only change vs R2: the 6-barrier LDS tree reduce is replaced by a 3-level
// in-wave shfl_xor (ks bits = lane bits 3..5) + one LDS cross-wave combine
// (3 barriers total). No memory access pattern changed.

namespace {

constexpr int CD   = 1024;  // C
constexpr int BN   = 4;     // B
constexpr int COLS = 8;     // output columns per block
constexpr int KS   = 32;    // k-slices (threads = COLS*KS = 256)
constexpr int KC   = CD / KS;

// Y[b][i] = sum_c X[b][c] * W[c][i] + bias[i]
__global__ __launch_bounds__(256)
void matvec_leg(const float* __restrict__ X,    // [4][1024]
                const float* __restrict__ W,    // [1024][1024] ([in][out])
                const float* __restrict__ bias, // [1024]
                float* __restrict__ Y)          // [4][1024]
{
    __shared__ float xs[BN * CD];       // 16 KB: whole X
    __shared__ float red[4 * 32];       // [wave][col*4+b]

    const int tid = threadIdx.x;

    // Stage X into LDS (coalesced float4: 4 iters x 256 threads x 16 B).
    {
        const float4* Xv = (const float4*)X;
        float4* xsv = (float4*)xs;
#pragma unroll
        for (int k = 0; k < (BN * CD / 4) / 256; ++k)
            xsv[k * 256 + tid] = Xv[k * 256 + tid];
    }
    __syncthreads();

    const int col = tid & (COLS - 1);   // 0..7  (lane bits 0-2)
    const int ks  = tid / COLS;         // 0..31 (lane bits 3-5 + wave bits)
    const int i   = blockIdx.x * COLS + col;

    // Interleaved K-walk: c = cc*KS + ks.
    //  - xs read: 8 distinct banks per wave, 8-lane broadcast each -> clean.
    //  - W read: per ks-row 8 consecutive floats (32 B segment), coalesced.
    float a0 = 0.f, a1 = 0.f, a2 = 0.f, a3 = 0.f;
#pragma unroll
    for (int cc = 0; cc < KC; ++cc) {
        const int c = cc * KS + ks;
        const float w = W[c * CD + i];
        a0 = fmaf(xs[0 * CD + c], w, a0);
        a1 = fmaf(xs[1 * CD + c], w, a1);
        a2 = fmaf(xs[2 * CD + c], w, a2);
        a3 = fmaf(xs[3 * CD + c], w, a3);
    }

    // In-wave reduce over ks bits 0..2 (lane bits 3..5): 3 shfl levels, no
    // barriers; col (lane bits 0..2) preserved. All lanes end with the wave sum.
#pragma unroll
    for (int s = 8; s < 64; s <<= 1) {
        a0 += __shfl_xor(a0, s, 64);
        a1 += __shfl_xor(a1, s, 64);
        a2 += __shfl_xor(a2, s, 64);
        a3 += __shfl_xor(a3, s, 64);
    }

    // Cross-wave combine: wave w, lanes 0..7 write their col's 4 batch sums.
    const int lane = tid & 63, wv = tid >> 6;
    if (lane < COLS) {
        red[wv * 32 + lane * 4 + 0] = a0;
        red[wv * 32 + lane * 4 + 1] = a1;
        red[wv * 32 + lane * 4 + 2] = a2;
        red[wv * 32 + lane * 4 + 3] = a3;
    }
    __syncthreads();

    // 32 finals: col = tid>>2, b = tid&3; reads red[w*32 + tid] consecutive.
    if (tid < 32) {
        const int c2 = tid >> 2;
        const int b  = tid & 3;
        float s = red[0 * 32 + tid] + red[1 * 32 + tid]
                + red[2 * 32 + tid] + red[3 * 32 + tid];
        const int ii = blockIdx.x * COLS + c2;
        Y[b * CD + ii] = s + bias[ii];
    }
}

} // namespace

extern "C" void kernel_launch(void* const* d_in, const int* in_sizes, int n_in,
                              void* d_out, int out_size, void* d_ws, size_t ws_size,
                              hipStream_t stream)
{
    // setup_inputs() order: x, Wq, bq, Wk, bk, Wv, bv, Wo, bo  (all fp32)
    const float* x  = (const float*)d_in[0];
    const float* Wv = (const float*)d_in[5];
    const float* bv = (const float*)d_in[6];
    const float* Wo = (const float*)d_in[7];
    const float* bo = (const float*)d_in[8];
    float* out = (float*)d_out;
    float* t   = (float*)d_ws;          // [4][1024] intermediate (16 KB)

    matvec_leg<<<CD / COLS, 256, 0, stream>>>(x, Wv, bv, t);
    matvec_leg<<<CD / COLS, 256, 0, stream>>>(t, Wo, bo, out);
}

// Round 9
// 14.119 us; speedup vs baseline: 1.7953x; 1.0408x over previous
//
#include <hip/hip_runtime.h>

// Problem: B=4, C=1024, H=16, D=64.
// Reference broadcasts x along the sequence axis, so q/k/v are constant over
// seq -> softmax(scores) is exactly uniform -> attn@v == v -> output is
//   out[b] = (x[b] @ Wv + bv) @ Wo + bo        (shape [4,1024], fp32)
// Wq/bq/Wk/bk are mathematically unused.
//
// FINAL STATE = round 2's measured-best structure (13.8 us), restored
// verbatim. Session evidence (R2-R8):
//   - two in-stream dispatches, 128 blk x 256 T, 8 cols/block, 32-way
//     interleaved split-K, LDS-staged X, LDS tree reduce  -> 13.8 us (best)
//   - grid-barrier fusion: 20.7/22.4 us; atomic+memset fusion: 25.3 us
//     (agent-scope sync / rocclr fill cost +7-12 us on non-coherent XCD L2s)
//   - 64blk x 1024T float4-W variants: 14.7-14.9 us (no better; noise-level)
//   - fixed graph-replay overhead ~10-11 us dominates; kernel exec ~1.5-2 us;
//     weights are L2/L3-resident (FETCH_SIZE ~15 KB/dispatch, no HBM traffic).

namespace {

constexpr int CD   = 1024;  // C
constexpr int BN   = 4;     // B
constexpr int COLS = 8;     // output columns per block
constexpr int KS   = 32;    // k-slices per block (threads = COLS*KS = 256)
constexpr int KC   = CD / KS; // 32 k-elements per slice

// Y[b][i] = sum_c X[b][c] * W[c][i] + bias[i]
__global__ __launch_bounds__(256)
void matvec_leg(const float* __restrict__ X,    // [4][1024]
                const float* __restrict__ W,    // [1024][1024] ([in][out])
                const float* __restrict__ bias, // [1024]
                float* __restrict__ Y)          // [4][1024]
{
    __shared__ float xs[BN * CD];       // 16 KB: whole X
    __shared__ float red[256 * BN];     // 4 KB: per-thread float4 partials

    const int tid = threadIdx.x;

    // Stage X into LDS (coalesced float4: 4 iters x 256 threads x 16 B).
    {
        const float4* Xv = (const float4*)X;
        float4* xsv = (float4*)xs;
#pragma unroll
        for (int k = 0; k < (BN * CD / 4) / 256; ++k)
            xsv[k * 256 + tid] = Xv[k * 256 + tid];
    }
    __syncthreads();

    const int col = tid & (COLS - 1);   // 0..7
    const int ks  = tid / COLS;         // 0..31
    const int i   = blockIdx.x * COLS + col;

    // Interleaved K-walk: c = cc*KS + ks.
    //  - xs read: 8 ks-groups of a wave hit 8 CONSECUTIVE floats -> no bank
    //    conflict (each is an 8-lane broadcast).
    //  - W read: per ks-group 8 consecutive floats (32 B segment), coalesced.
    float a0 = 0.f, a1 = 0.f, a2 = 0.f, a3 = 0.f;
#pragma unroll
    for (int cc = 0; cc < KC; ++cc) {
        const int c = cc * KS + ks;
        const float w = W[c * CD + i];
        a0 = fmaf(xs[0 * CD + c], w, a0);
        a1 = fmaf(xs[1 * CD + c], w, a1);
        a2 = fmaf(xs[2 * CD + c], w, a2);
        a3 = fmaf(xs[3 * CD + c], w, a3);
    }

    // LDS tree-reduce over ks (red4 indexed [ks][col]).
    float4* r4 = (float4*)red;
    r4[tid] = make_float4(a0, a1, a2, a3);
    __syncthreads();
#pragma unroll
    for (int s = KS / 2; s >= 1; s >>= 1) {
        if (ks < s) {
            float4 o = r4[tid + s * COLS];
            float4 m = r4[tid];
            m.x += o.x; m.y += o.y; m.z += o.z; m.w += o.w;
            r4[tid] = m;
        }
        __syncthreads();
    }

    // red4[col] now holds the 4-batch result for column (blk*COLS+col).
    if (tid < COLS * BN) {
        const int c2 = tid >> 2;        // column 0..7
        const int b  = tid & 3;         // batch 0..3
        const int ii = blockIdx.x * COLS + c2;
        Y[b * CD + ii] = red[c2 * 4 + b] + bias[ii];
    }
}

} // namespace

extern "C" void kernel_launch(void* const* d_in, const int* in_sizes, int n_in,
                              void* d_out, int out_size, void* d_ws, size_t ws_size,
                              hipStream_t stream)
{
    // setup_inputs() order: x, Wq, bq, Wk, bk, Wv, bv, Wo, bo  (all fp32)
    const float* x  = (const float*)d_in[0];
    const float* Wv = (const float*)d_in[5];
    const float* bv = (const float*)d_in[6];
    const float* Wo = (const float*)d_in[7];
    const float* bo = (const float*)d_in[8];
    float* out = (float*)d_out;
    float* t   = (float*)d_ws;          // [4][1024] intermediate (16 KB)

    matvec_leg<<<CD / COLS, 256, 0, stream>>>(x, Wv, bv, t);
    matvec_leg<<<CD / COLS, 256, 0, stream>>>(t, Wo, bo, out);
}